// Round 5
// baseline (501.153 us; speedup 1.0000x reference)
//
#include <hip/hip_runtime.h>
#include <hip/hip_bf16.h>

typedef unsigned short u16;
typedef __attribute__((ext_vector_type(8))) short short8v;
typedef __attribute__((ext_vector_type(4))) float f32x4;

typedef __attribute__((address_space(3))) char lds_char;
typedef const __attribute__((address_space(1))) char g_char;

__device__ __forceinline__ u16 f2bf(float f) {
    union { float f; unsigned int u; } x; x.f = f;
    unsigned int u = x.u;
    return (u16)((u + 0x7FFFu + ((u >> 16) & 1u)) >> 16);
}
__device__ __forceinline__ float bf2f(u16 h) {
    union { unsigned int u; float f; } x; x.u = ((unsigned int)h) << 16;
    return x.f;
}
__device__ __forceinline__ void gload16(const void* g, void* l) {
    __builtin_amdgcn_global_load_lds((g_char*)g, (lds_char*)l, 16, 0, 0);
}
template<int N> __device__ __forceinline__ void vm_wait() {
    asm volatile("s_waitcnt vmcnt(%0)" :: "i"(N) : "memory");
}
__device__ __forceinline__ void lgkm_barrier() {
    __builtin_amdgcn_sched_barrier(0);
    asm volatile("s_waitcnt lgkmcnt(0)" ::: "memory");
    __builtin_amdgcn_s_barrier();
    __builtin_amdgcn_sched_barrier(0);
}

// ---------------------------------------------------------------------------
// 128x64 bf16 MFMA GEMM tile, BK=64. 256 thr = 4 waves (2x2), wave tile 64x32
// (4x2 frags of 16x16x32). LDS (all bf16, XOR-swizzled): Abuf[2]@{0,16K},
// Bbuf[3]@{32K, 40K, 48K} = 56 KB -> 2 blocks/CU (8 waves/CU, 2/SIMD).
// A reg-staged (global->VGPR->(cvt)->swizzled ds_write), B via global_load_lds
// (pre-swizzled source). One barrier per K-step, counted vmcnt.
//
// Pipeline (iter kt): buffers read this iter were vmcnt-FORCED one barrier
// earlier (cross-wave DMA visibility requires force -> barrier -> read):
//   issue A(kt+2)->rA[kt&1], B(kt+2)->Bbuf[(kt+2)%3]       (DMA)
//   vmcnt(LA+LB)   -> forces A(kt+1) regs + B(kt+1) DMA
//   writeA A(kt+1) -> Abuf[(kt+1)&1]                        (ds_write)
//   compute(Abuf[kt&1], Bbuf[kt%3])
//   lgkmcnt(0); s_barrier
// EPI: 0=store bf16, 1=*V store bf16, 2=+bias,gelu store bf16, 3=+bias f32.
// AF32: A operand fp32, cvt to bf16 between global load and ds_write.
// Requires nsteps = K/64 even and >= 4.
// ---------------------------------------------------------------------------
template<int EPI, bool AF32>
__global__ __launch_bounds__(256, 2) void gemm_k(
    const void* __restrict__ Ap, int lda,
    const u16* __restrict__ Bt, int ldb,
    void* __restrict__ Cp, int ldc, int K,
    const float* __restrict__ bias,
    const u16* __restrict__ vmul, int ldv)
{
    __shared__ alignas(16) char smem[57344];
    constexpr int LA = AF32 ? 8 : 4;   // A global loads per thread per stage
    constexpr int LB = 2;              // B gload16 per thread per stage

    const int t    = threadIdx.x;
    const int lane = t & 63;
    const int wid  = t >> 6;
    const int m0   = blockIdx.x * 128;
    const int n0   = blockIdx.y * 64;
    const int wr   = wid >> 1, wc = wid & 1;
    const int lr   = lane & 15, q4 = lane >> 4;

    f32x4 acc[4][2];
    #pragma unroll
    for (int i = 0; i < 4; ++i)
        #pragma unroll
        for (int j = 0; j < 2; ++j)
            acc[i][j] = (f32x4){0.f, 0.f, 0.f, 0.f};

    uint4 rA0[LA], rA1[LA];

    // ---- A: issue global loads for tile kt into reg set r ----
    auto loadA = [&](uint4* r, int kt) {
        const int k0 = kt << 6;
        if constexpr (AF32) {
            const float* A32 = (const float*)Ap;
            #pragma unroll
            for (int p = 0; p < 8; ++p) {
                int o   = p * 4096 + t * 16;       // byte offset in fp32 tile
                int row = o >> 8;
                int sg  = (o >> 4) & 15;           // 16B segment (4 floats)
                r[p] = *(const uint4*)(A32 + (size_t)(m0 + row) * (size_t)lda
                                       + k0 + sg * 4);
            }
        } else {
            const u16* A16 = (const u16*)Ap;
            #pragma unroll
            for (int p = 0; p < 4; ++p) {
                int o   = p * 4096 + t * 16;       // byte offset in bf16 tile
                int row = o >> 7;
                int sg  = (o >> 4) & 7;            // 16B segment (8 bf16)
                r[p] = *(const uint4*)(A16 + (size_t)(m0 + row) * (size_t)lda
                                       + k0 + sg * 8);
            }
        }
    };
    // ---- B: DMA tile kt into Bbuf at byte offset boff (pre-swizzled src) ----
    auto stageB = [&](int boff, int kt) {
        const int k0 = kt << 6;
        #pragma unroll
        for (int p = 0; p < 2; ++p) {
            int o   = p * 4096 + t * 16;
            int row = o >> 7;
            int cb  = (o & 127) ^ ((row & 7) << 4);
            gload16(Bt + (size_t)(n0 + row) * (size_t)ldb + k0 + (cb >> 1),
                    smem + 32768 + boff + o);
        }
    };
    // ---- A: (cvt) + swizzled ds_write of reg set into Abuf[aoff] ----
    auto writeA = [&](const uint4* r, int aoff) {
        char* base = smem + aoff;
        if constexpr (AF32) {
            #pragma unroll
            for (int p = 0; p < 8; ++p) {
                int o   = p * 4096 + t * 16;
                int row = o >> 8;
                int cb  = (o >> 1) & 127;          // bf16 byte col
                const float* f = (const float*)&r[p];
                uint2 w;
                w.x = (unsigned)f2bf(f[0]) | ((unsigned)f2bf(f[1]) << 16);
                w.y = (unsigned)f2bf(f[2]) | ((unsigned)f2bf(f[3]) << 16);
                *(uint2*)(base + row * 128 + (cb ^ ((row & 7) << 4))) = w;
            }
        } else {
            #pragma unroll
            for (int p = 0; p < 4; ++p) {
                int o   = p * 4096 + t * 16;
                int row = o >> 7;
                int cb  = o & 127;
                *(uint4*)(base + row * 128 + (cb ^ ((row & 7) << 4))) = r[p];
            }
        }
    };
    // ---- one K-step of MFMAs ----
    auto compute = [&](int aoff, int boff) {
        const char* Ab = smem + aoff;
        const char* Bb = smem + 32768 + boff;
        #pragma unroll
        for (int kh = 0; kh < 2; ++kh) {
            short8v a[4], b[2];
            #pragma unroll
            for (int i = 0; i < 4; ++i) {
                int ar = wr * 64 + i * 16 + lr;
                a[i] = *(const short8v*)(Ab + ar * 128 +
                        ((kh * 64 + q4 * 16) ^ ((ar & 7) << 4)));
            }
            #pragma unroll
            for (int i = 0; i < 2; ++i) {
                int br = wc * 32 + i * 16 + lr;
                b[i] = *(const short8v*)(Bb + br * 128 +
                        ((kh * 64 + q4 * 16) ^ ((br & 7) << 4)));
            }
            #pragma unroll
            for (int mi = 0; mi < 4; ++mi)
                #pragma unroll
                for (int ni = 0; ni < 2; ++ni)
                    acc[mi][ni] = __builtin_amdgcn_mfma_f32_16x16x32_bf16(
                        a[mi], b[ni], acc[mi][ni], 0, 0, 0);
        }
    };
    auto rot = [](int x) { return x == 16384 ? 0 : x + 8192; };

    const int nsteps = K >> 6;   // even, >= 4 for all call sites

    // ---- prologue ----
    loadA(rA0, 0); stageB(0, 0);
    loadA(rA1, 1); stageB(8192, 1);
    vm_wait<LA + LB>();          // forces A(0), B(0); leaves {A(1), B(1)}
    writeA(rA0, 0);
    lgkm_barrier();

    int brd = 0;                 // Bbuf offset for compute(kt)
    int bwr = 16384;             // Bbuf offset for stage of kt+2

    // ---- main loop (iters kt = 0 .. nsteps-3), unrolled x2 ----
    for (int kt = 0; kt < nsteps - 3; kt += 2) {
        // even iter
        loadA(rA0, kt + 2); stageB(bwr, kt + 2);
        vm_wait<LA + LB>();
        writeA(rA1, 16384);
        compute(0, brd);
        lgkm_barrier();
        brd = rot(brd); bwr = rot(bwr);
        // odd iter
        loadA(rA1, kt + 3); stageB(bwr, kt + 3);
        vm_wait<LA + LB>();
        writeA(rA0, 0);
        compute(16384, brd);
        lgkm_barrier();
        brd = rot(brd); bwr = rot(bwr);
    }
    // ---- tail: kt = nsteps-2 (even), nsteps-1 (odd) ----
    vm_wait<0>();                // forces A(nsteps-1) regs + B(nsteps-1) DMA
    writeA(rA1, 16384);
    compute(0, brd);
    lgkm_barrier();
    brd = rot(brd);
    compute(16384, brd);

    // ---- epilogue ----
    #pragma unroll
    for (int mi = 0; mi < 4; ++mi) {
        #pragma unroll
        for (int ni = 0; ni < 2; ++ni) {
            const int gc = n0 + wc * 32 + ni * 16 + lr;
            #pragma unroll
            for (int j = 0; j < 4; ++j) {
                const int gr = m0 + wr * 64 + mi * 16 + q4 * 4 + j;
                float v = acc[mi][ni][j];
                if constexpr (EPI == 0) {
                    ((u16*)Cp)[(size_t)gr * ldc + gc] = f2bf(v);
                } else if constexpr (EPI == 1) {
                    v *= bf2f(vmul[(size_t)gr * ldv + gc]);
                    ((u16*)Cp)[(size_t)gr * ldc + gc] = f2bf(v);
                } else if constexpr (EPI == 2) {
                    float x = v + bias[gc];
                    float g = 0.5f * x * (1.0f + erff(x * 0.70710678118f));
                    ((u16*)Cp)[(size_t)gr * ldc + gc] = f2bf(g);
                } else {
                    ((float*)Cp)[(size_t)gr * ldc + gc] = v + bias[gc];
                }
            }
        }
    }
}

// ---------------------------------------------------------------------------
// Convert Wq|Wk|Wv (concat) and W1 to bf16.
// ---------------------------------------------------------------------------
__global__ void k_convert(const float* __restrict__ Wq, const float* __restrict__ Wk,
                          const float* __restrict__ Wv, const float* __restrict__ W1,
                          u16* __restrict__ WqkvB, u16* __restrict__ W1B)
{
    const int C2 = 196608;
    const int C3 = 65536;
    for (int i = blockIdx.x * blockDim.x + threadIdx.x; i < C2 + C3;
         i += gridDim.x * blockDim.x) {
        const float* src; u16* dst;
        if (i < C2) {
            int e = i * 4;
            if (e < 262144)      src = Wq + e;
            else if (e < 524288) src = Wk + (e - 262144);
            else                 src = Wv + (e - 524288);
            dst = WqkvB + e;
        } else {
            int e = (i - C2) * 4;
            src = W1 + e; dst = W1B + e;
        }
        float4 v = *reinterpret_cast<const float4*>(src);
        ushort4 h;
        h.x = f2bf(v.x); h.y = f2bf(v.y); h.z = f2bf(v.z); h.w = f2bf(v.w);
        *reinterpret_cast<ushort4*>(dst) = h;
    }
}

// ---------------------------------------------------------------------------
// TXT[c][m] = bf16(task_x[m][c])  — 64x64 tiles through LDS.
// ---------------------------------------------------------------------------
__global__ void k_transpose(const float* __restrict__ tx, u16* __restrict__ txt)
{
    __shared__ float tile[64][65];
    const int n0 = blockIdx.x * 64;
    const int c0 = blockIdx.y * 64;
    const int t = threadIdx.x;
    #pragma unroll
    for (int p = 0; p < 4; ++p) {
        int q = p * 256 + t;
        int r = q >> 4, s = q & 15;
        float4 v = *reinterpret_cast<const float4*>(tx + (size_t)(n0 + r) * 512 + c0 + s * 4);
        tile[r][s * 4 + 0] = v.x; tile[r][s * 4 + 1] = v.y;
        tile[r][s * 4 + 2] = v.z; tile[r][s * 4 + 3] = v.w;
    }
    __syncthreads();
    #pragma unroll
    for (int p = 0; p < 4; ++p) {
        int q = p * 256 + t;
        int cc = q >> 4, s = q & 15;
        ushort4 h;
        h.x = f2bf(tile[s * 4 + 0][cc]); h.y = f2bf(tile[s * 4 + 1][cc]);
        h.z = f2bf(tile[s * 4 + 2][cc]); h.w = f2bf(tile[s * 4 + 3][cc]);
        *reinterpret_cast<ushort4*>(txt + (size_t)(c0 + cc) * 8192 + n0 + s * 4) = h;
    }
}

// ---------------------------------------------------------------------------
// colsq[j] = sum_n QKV[n,j]^2, j in [0,1024)
// ---------------------------------------------------------------------------
__global__ void k_colsq(const u16* __restrict__ QKV, float* __restrict__ colsq)
{
    const int t = threadIdx.x;
    const int c8 = t & 127, rs = t >> 7;
    float a[8];
    #pragma unroll
    for (int j = 0; j < 8; ++j) a[j] = 0.f;
    const int row0 = blockIdx.x * 64;
    for (int rr = rs; rr < 64; rr += 2) {
        uint4 u = *reinterpret_cast<const uint4*>(QKV + (size_t)(row0 + rr) * 1536 + c8 * 8);
        unsigned int w[4] = {u.x, u.y, u.z, u.w};
        #pragma unroll
        for (int q = 0; q < 4; ++q) {
            float f0 = bf2f((u16)(w[q] & 0xffffu));
            float f1 = bf2f((u16)(w[q] >> 16));
            a[2 * q]     += f0 * f0;
            a[2 * q + 1] += f1 * f1;
        }
    }
    #pragma unroll
    for (int j = 0; j < 8; ++j) atomicAdd(&colsq[c8 * 8 + j], a[j]);
}

// ---------------------------------------------------------------------------
// Per-head Gram partials: S[h,d,e] += sum_{n in chunk} K[n,h64+d]*Q[n,h64+e]
// ---------------------------------------------------------------------------
__global__ void k_gram(const u16* __restrict__ QKV, float* __restrict__ Sb)
{
    __shared__ u16 Qt[4][64];
    __shared__ u16 Kt[4][64];
    const int h = blockIdx.x >> 6;
    const int chunk = blockIdx.x & 63;
    const int t = threadIdx.x;
    const int e = t & 63;
    const int dg = t >> 6;
    float acc[16];
    #pragma unroll
    for (int k = 0; k < 16; ++k) acc[k] = 0.f;
    const int rowbase = chunk * 128;
    for (int p = 0; p < 32; ++p) {
        __syncthreads();
        if (t < 64) {
            const int mat = t >> 5, sub = t & 31, r = sub >> 3, seg = sub & 7;
            const int row = rowbase + p * 4 + r;
            const int col = (mat ? 512 : 0) + h * 64 + seg * 8;
            uint4 v = *reinterpret_cast<const uint4*>(QKV + (size_t)row * 1536 + col);
            u16* dst = mat ? &Kt[r][seg * 8] : &Qt[r][seg * 8];
            *reinterpret_cast<uint4*>(dst) = v;
        }
        __syncthreads();
        #pragma unroll
        for (int r = 0; r < 4; ++r) {
            const float q = bf2f(Qt[r][e]);
            short8v kv0 = *reinterpret_cast<const short8v*>(&Kt[r][dg * 16]);
            short8v kv1 = *reinterpret_cast<const short8v*>(&Kt[r][dg * 16 + 8]);
            #pragma unroll
            for (int k = 0; k < 8; ++k) {
                acc[k]     += bf2f((u16)kv0[k]) * q;
                acc[k + 8] += bf2f((u16)kv1[k]) * q;
            }
        }
    }
    #pragma unroll
    for (int k = 0; k < 16; ++k)
        atomicAdd(&Sb[h * 4096 + (dg * 16 + k) * 64 + e], acc[k]);
}

// ---------------------------------------------------------------------------
// attn[h,d,e] = softmax_e( S/(||k_d|| ||q_e||) * rescale[h] )
// ---------------------------------------------------------------------------
__global__ void k_softmax(const float* __restrict__ Sb, const float* __restrict__ colsq,
                          const float* __restrict__ rescale, float* __restrict__ Abuf)
{
    const int h = blockIdx.x;
    const int t = threadIdx.x;   // 64
    const float rsc = rescale[h];
    const float nq = fmaxf(sqrtf(colsq[h * 64 + t]), 1e-12f);
    for (int d = 0; d < 64; ++d) {
        const float nk = fmaxf(sqrtf(colsq[512 + h * 64 + d]), 1e-12f);
        float v = Sb[h * 4096 + d * 64 + t] / (nk * nq) * rsc;
        float m = v;
        #pragma unroll
        for (int off = 32; off > 0; off >>= 1) m = fmaxf(m, __shfl_xor(m, off, 64));
        float p = expf(v - m);
        float s = p;
        #pragma unroll
        for (int off = 32; off > 0; off >>= 1) s += __shfl_xor(s, off, 64);
        Abuf[h * 4096 + d * 64 + t] = p / s;
    }
}

// ---------------------------------------------------------------------------
// BtC[j][c]: c<512 -> fold attn with Wp; c>=512 -> W2. bsum[j] = bp[j]+b2[j].
// ---------------------------------------------------------------------------
__global__ void k_buildbt(const float* __restrict__ Abuf, const float* __restrict__ Wp,
                          const float* __restrict__ W2, const float* __restrict__ bp,
                          const float* __restrict__ b2, u16* __restrict__ BtC,
                          float* __restrict__ bsum)
{
    const int g = blockIdx.x * 256 + threadIdx.x;
    const int j = g >> 10, c = g & 1023;
    if (c < 512) {
        const int h = c >> 6, e = c & 63;
        const float* Ah = Abuf + h * 4096 + e;
        const float* Wph = Wp + (size_t)j * 512 + h * 64;
        float s = 0.f;
        #pragma unroll 8
        for (int d = 0; d < 64; ++d) s += Ah[d * 64] * Wph[d];
        BtC[(size_t)j * 1024 + c] = f2bf(s);
        if (c == 0) bsum[j] = bp[j] + b2[j];
    } else {
        BtC[(size_t)j * 1024 + c] = f2bf(W2[(size_t)j * 512 + (c - 512)]);
    }
}

// ---------------------------------------------------------------------------
extern "C" void kernel_launch(void* const* d_in, const int* in_sizes, int n_in,
                              void* d_out, int out_size, void* d_ws, size_t ws_size,
                              hipStream_t stream)
{
    const float* x_in    = (const float*)d_in[0];
    const float* task_x  = (const float*)d_in[1];
    const float* Ges     = (const float*)d_in[2];
    const float* Wq      = (const float*)d_in[3];
    const float* Wk      = (const float*)d_in[4];
    const float* Wv      = (const float*)d_in[5];
    const float* rescale = (const float*)d_in[6];
    const float* Wp      = (const float*)d_in[7];
    const float* bp      = (const float*)d_in[8];
    const float* W1      = (const float*)d_in[9];
    const float* b1      = (const float*)d_in[10];
    const float* W2      = (const float*)d_in[11];
    const float* b2      = (const float*)d_in[12];
    float* out = (float*)d_out;
    char* ws = (char*)d_ws;

    u16*   TXT   = (u16*)  (ws + 8388608);      //  512x8192  bf16
    u16*   QKV   = (u16*)  (ws + 16777216);     //  8192x1536 bf16
    u16*   AH    = (u16*)  (ws + 41943040);     //  8192x1024 bf16
    u16*   WqkvB = (u16*)  (ws + 58720256);     //  1536x512  bf16
    u16*   W1B   = (u16*)  (ws + 60293120);     //  512x512   bf16
    u16*   BtC   = (u16*)  (ws + 60817408);     //  512x1024  bf16
    float* colsq = (float*)(ws + 61865984);     //  1024 f32
    float* Sb    = (float*)(ws + 61870080);     //  8x64x64 f32
    float* Abuf  = (float*)(ws + 62001152);     //  8x64x64 f32
    float* bsum  = (float*)(ws + 62132224);     //  512 f32
    (void)in_sizes; (void)n_in; (void)out_size; (void)ws_size;

    hipMemsetAsync(colsq, 0, 4096 + 131072, stream);

    k_convert  <<<1024, 256, 0, stream>>>(Wq, Wk, Wv, W1, WqkvB, W1B);
    k_transpose<<<dim3(128, 8), 256, 0, stream>>>(task_x, TXT);

    // QKV = x @ [Wq;Wk;Wv]^T   (M=8192, N=1536, K=512; A = x_in fp32)
    gemm_k<0, true><<<dim3(64, 24), 256, 0, stream>>>(
        x_in, 512, WqkvB, 512, QKV, 1536, 512, nullptr, nullptr, 0);

    k_colsq  <<<128, 256, 0, stream>>>(QKV, colsq);
    k_gram   <<<512, 256, 0, stream>>>(QKV, Sb);
    k_softmax<<<8, 64, 0, stream>>>(Sb, colsq, rescale, Abuf);
    k_buildbt<<<2048, 256, 0, stream>>>(Abuf, Wp, W2, bp, b2, BtC, bsum);

    // guided = (Ges @ task_x) * V   (M=8192, N=512, K=8192; A fp32)
    gemm_k<1, true><<<dim3(64, 8), 256, 0, stream>>>(
        Ges, 8192, TXT, 8192, AH, 1024, 8192, nullptr, QKV + 1024, 1536);

    // hidden = gelu(V @ W1^T + b1)  (M=8192, N=512, K=512)
    gemm_k<2, false><<<dim3(64, 8), 256, 0, stream>>>(
        QKV + 1024, 1536, W1B, 512, AH + 512, 1024, 512, b1, nullptr, 0);

    // out = [guided|hidden] @ BtC^T + (bp+b2)  (M=8192, N=512, K=1024)
    gemm_k<3, false><<<dim3(64, 8), 256, 0, stream>>>(
        AH, 1024, BtC, 1024, out, 512, 1024, bsum, nullptr, 0);
}

// Round 6
// 392.392 us; speedup vs baseline: 1.2772x; 1.2772x over previous
//
#include <hip/hip_runtime.h>
#include <hip/hip_bf16.h>

typedef unsigned short u16;
typedef __attribute__((ext_vector_type(8))) short short8v;
typedef __attribute__((ext_vector_type(4))) float f32x4;

typedef __attribute__((address_space(3))) char lds_char;
typedef const __attribute__((address_space(1))) char g_char;

__device__ __forceinline__ u16 f2bf(float f) {
    union { float f; unsigned int u; } x; x.f = f;
    unsigned int u = x.u;
    return (u16)((u + 0x7FFFu + ((u >> 16) & 1u)) >> 16);
}
__device__ __forceinline__ float bf2f(u16 h) {
    union { unsigned int u; float f; } x; x.u = ((unsigned int)h) << 16;
    return x.f;
}
__device__ __forceinline__ void gload16(const void* g, void* l) {
    __builtin_amdgcn_global_load_lds((g_char*)g, (lds_char*)l, 16, 0, 0);
}
template<int N> __device__ __forceinline__ void vm_wait() {
    asm volatile("s_waitcnt vmcnt(%0)" :: "i"(N) : "memory");
}
__device__ __forceinline__ void barrier_raw() {
    __builtin_amdgcn_sched_barrier(0);
    __builtin_amdgcn_s_barrier();
    __builtin_amdgcn_sched_barrier(0);
}
__device__ __forceinline__ void lgkm_barrier() {
    __builtin_amdgcn_sched_barrier(0);
    asm volatile("s_waitcnt lgkmcnt(0)" ::: "memory");
    __builtin_amdgcn_s_barrier();
    __builtin_amdgcn_sched_barrier(0);
}

// ---------------------------------------------------------------------------
// 128x64 bf16 MFMA GEMM tile, BK=64. 256 thr = 4 waves (2x2), wave tile 64x32
// (4x2 frags of 16x16x32). ALL staging via global_load_lds (pre-swizzled
// source, linear LDS dest). DEPTH-buffered (3 for bf16 = 72KB, 2 for AF32
// fallback = 80KB) -> 2 blocks/CU either way. Counted vmcnt: tiles stay in
// flight DEPTH-1 full iterations (covers HBM latency at DEPTH=3).
//
// Ledger, main iter kt (invariant: kt visible+forced, kt+1..kt+DEPTH-1 in
// flight, rd = kt % DEPTH):
//   1. compute(rd)                       reads tile kt
//   2. lgkmcnt(0); s_barrier             all waves' LDS reads of buf rd done
//   3. stage(rd, kt+DEPTH)               safe overwrite (DMA, async)
//   4. vmcnt((DEPTH-1)*LPS)              forces ALL of tile kt+1
//   5. s_barrier                         kt+1 visible to every wave
// EPI: 0=store bf16, 1=*V store bf16, 2=+bias,gelu store bf16, 3=+bias f32.
// AF32: A fp32 staged in LDS as fp32, cvt on fragment path (fallback only).
// Requires nsteps = K/64 >= DEPTH+1.
// ---------------------------------------------------------------------------
template<int EPI, bool AF32>
__global__ __launch_bounds__(256, 2) void gemm_k(
    const void* __restrict__ Ap, int lda,
    const u16* __restrict__ Bt, int ldb,
    void* __restrict__ Cp, int ldc, int K,
    const float* __restrict__ bias,
    const u16* __restrict__ vmul, int ldv)
{
    constexpr int DEPTH = AF32 ? 2 : 3;
    constexpr int ATB   = AF32 ? 32768 : 16384;  // A tile bytes
    constexpr int BTB   = 8192;                  // B tile bytes
    constexpr int LA    = AF32 ? 8 : 4;          // A gload16 per thread/stage
    constexpr int LPS   = LA + 2;                // + B gload16
    __shared__ alignas(16) char smem[DEPTH * (ATB + BTB)];

    const int t    = threadIdx.x;
    const int lane = t & 63;
    const int wid  = t >> 6;
    const int m0   = blockIdx.x * 128;
    const int n0   = blockIdx.y * 64;
    const int wr   = wid >> 1, wc = wid & 1;
    const int lr   = lane & 15, q4 = lane >> 4;

    f32x4 acc[4][2];
    #pragma unroll
    for (int i = 0; i < 4; ++i)
        #pragma unroll
        for (int j = 0; j < 2; ++j)
            acc[i][j] = (f32x4){0.f, 0.f, 0.f, 0.f};

    // ---- DMA tile kt into buffer d (pre-swizzled global source) ----
    auto stage = [&](int d, int kt) {
        const int k0 = kt << 6;
        char* Ad = smem + d * ATB;
        if constexpr (AF32) {
            const float* A32 = (const float*)Ap;
            #pragma unroll
            for (int p = 0; p < 8; ++p) {
                int o   = p * 4096 + t * 16;
                int row = o >> 8;
                int cb  = (o & 255) ^ ((row & 15) << 4);
                gload16(A32 + (size_t)(m0 + row) * (size_t)lda + k0 + (cb >> 2),
                        Ad + o);
            }
        } else {
            const u16* A16 = (const u16*)Ap;
            #pragma unroll
            for (int p = 0; p < 4; ++p) {
                int o   = p * 4096 + t * 16;
                int row = o >> 7;
                int cb  = (o & 127) ^ ((row & 7) << 4);
                gload16(A16 + (size_t)(m0 + row) * (size_t)lda + k0 + (cb >> 1),
                        Ad + o);
            }
        }
        char* Bd = smem + DEPTH * ATB + d * BTB;
        #pragma unroll
        for (int p = 0; p < 2; ++p) {
            int o   = p * 4096 + t * 16;
            int row = o >> 7;
            int cb  = (o & 127) ^ ((row & 7) << 4);
            gload16(Bt + (size_t)(n0 + row) * (size_t)ldb + k0 + (cb >> 1),
                    Bd + o);
        }
    };
    // ---- one K-step of MFMAs from buffer d ----
    auto compute = [&](int d) {
        const char* Ab = smem + d * ATB;
        const char* Bb = smem + DEPTH * ATB + d * BTB;
        #pragma unroll
        for (int kh = 0; kh < 2; ++kh) {
            short8v a[4], b[2];
            #pragma unroll
            for (int i = 0; i < 4; ++i) {
                int ar = wr * 64 + i * 16 + lr;
                if constexpr (AF32) {
                    int cb0 = kh * 128 + q4 * 32;
                    f32x4 f0 = *(const f32x4*)(Ab + ar * 256 +
                                (cb0 ^ ((ar & 15) << 4)));
                    f32x4 f1 = *(const f32x4*)(Ab + ar * 256 +
                                ((cb0 + 16) ^ ((ar & 15) << 4)));
                    short8v av;
                    #pragma unroll
                    for (int j = 0; j < 4; ++j) {
                        av[j]     = (short)f2bf(f0[j]);
                        av[j + 4] = (short)f2bf(f1[j]);
                    }
                    a[i] = av;
                } else {
                    a[i] = *(const short8v*)(Ab + ar * 128 +
                            ((kh * 64 + q4 * 16) ^ ((ar & 7) << 4)));
                }
            }
            #pragma unroll
            for (int i = 0; i < 2; ++i) {
                int br = wc * 32 + i * 16 + lr;
                b[i] = *(const short8v*)(Bb + br * 128 +
                        ((kh * 64 + q4 * 16) ^ ((br & 7) << 4)));
            }
            #pragma unroll
            for (int mi = 0; mi < 4; ++mi)
                #pragma unroll
                for (int ni = 0; ni < 2; ++ni)
                    acc[mi][ni] = __builtin_amdgcn_mfma_f32_16x16x32_bf16(
                        a[mi], b[ni], acc[mi][ni], 0, 0, 0);
        }
    };
    auto nx = [](int d) { return d + 1 == DEPTH ? 0 : d + 1; };

    const int nsteps = K >> 6;   // all call sites: nsteps >= DEPTH+1

    // ---- prologue: fill all DEPTH buffers, force tile 0 ----
    #pragma unroll
    for (int d = 0; d < DEPTH; ++d) stage(d, d);
    vm_wait<(DEPTH - 1) * LPS>();
    barrier_raw();

    int rd = 0;
    for (int kt = 0; kt < nsteps - DEPTH; ++kt) {
        compute(rd);
        lgkm_barrier();
        stage(rd, kt + DEPTH);
        vm_wait<(DEPTH - 1) * LPS>();
        barrier_raw();
        rd = nx(rd);
    }
    // ---- drain ----
    if constexpr (DEPTH == 3) {
        compute(rd); rd = nx(rd);
        vm_wait<LPS>(); barrier_raw();
    }
    compute(rd); rd = nx(rd);
    vm_wait<0>(); barrier_raw();
    compute(rd);

    // ---- epilogue ----
    #pragma unroll
    for (int mi = 0; mi < 4; ++mi) {
        #pragma unroll
        for (int ni = 0; ni < 2; ++ni) {
            const int gc = n0 + wc * 32 + ni * 16 + lr;
            #pragma unroll
            for (int j = 0; j < 4; ++j) {
                const int gr = m0 + wr * 64 + mi * 16 + q4 * 4 + j;
                float v = acc[mi][ni][j];
                if constexpr (EPI == 0) {
                    ((u16*)Cp)[(size_t)gr * ldc + gc] = f2bf(v);
                } else if constexpr (EPI == 1) {
                    v *= bf2f(vmul[(size_t)gr * ldv + gc]);
                    ((u16*)Cp)[(size_t)gr * ldc + gc] = f2bf(v);
                } else if constexpr (EPI == 2) {
                    float x = v + bias[gc];
                    float g = 0.5f * x * (1.0f + erff(x * 0.70710678118f));
                    ((u16*)Cp)[(size_t)gr * ldc + gc] = f2bf(g);
                } else {
                    ((float*)Cp)[(size_t)gr * ldc + gc] = v + bias[gc];
                }
            }
        }
    }
}

// ---------------------------------------------------------------------------
// Ges fp32 -> bf16, streaming (8 floats / thread-iter, 16B stores).
// ---------------------------------------------------------------------------
__global__ void k_cges(const float* __restrict__ g, u16* __restrict__ gb)
{
    const int total = 8388608;   // chunks of 8 floats (8192*8192/8)
    for (int i = blockIdx.x * 256 + threadIdx.x; i < total;
         i += gridDim.x * 256) {
        const float4* s = (const float4*)(g + (size_t)i * 8);
        float4 a = s[0], b = s[1];
        uint4 o;
        o.x = (unsigned)f2bf(a.x) | ((unsigned)f2bf(a.y) << 16);
        o.y = (unsigned)f2bf(a.z) | ((unsigned)f2bf(a.w) << 16);
        o.z = (unsigned)f2bf(b.x) | ((unsigned)f2bf(b.y) << 16);
        o.w = (unsigned)f2bf(b.z) | ((unsigned)f2bf(b.w) << 16);
        *(uint4*)(gb + (size_t)i * 8) = o;
    }
}

// ---------------------------------------------------------------------------
// Convert x_in, Wq|Wk|Wv (concat), W1 to bf16.
// ---------------------------------------------------------------------------
__global__ void k_convert(const float* __restrict__ x_in,
                          const float* __restrict__ Wq, const float* __restrict__ Wk,
                          const float* __restrict__ Wv, const float* __restrict__ W1,
                          u16* __restrict__ XB, u16* __restrict__ WqkvB,
                          u16* __restrict__ W1B)
{
    const int C1 = 1048576;   // x_in float4 chunks
    const int C2 = 196608;    // Wqkv
    const int C3 = 65536;     // W1
    for (int i = blockIdx.x * blockDim.x + threadIdx.x; i < C1 + C2 + C3;
         i += gridDim.x * blockDim.x) {
        const float* src; u16* dst;
        if (i < C1) { src = x_in + (size_t)i * 4; dst = XB + (size_t)i * 4; }
        else if (i < C1 + C2) {
            int e = (i - C1) * 4;
            if (e < 262144)      src = Wq + e;
            else if (e < 524288) src = Wk + (e - 262144);
            else                 src = Wv + (e - 524288);
            dst = WqkvB + e;
        } else {
            int e = (i - C1 - C2) * 4;
            src = W1 + e; dst = W1B + e;
        }
        float4 v = *reinterpret_cast<const float4*>(src);
        ushort4 h;
        h.x = f2bf(v.x); h.y = f2bf(v.y); h.z = f2bf(v.z); h.w = f2bf(v.w);
        *reinterpret_cast<ushort4*>(dst) = h;
    }
}

// ---------------------------------------------------------------------------
// TXT[c][m] = bf16(task_x[m][c])  — 64x64 tiles through LDS.
// ---------------------------------------------------------------------------
__global__ void k_transpose(const float* __restrict__ tx, u16* __restrict__ txt)
{
    __shared__ float tile[64][65];
    const int n0 = blockIdx.x * 64;
    const int c0 = blockIdx.y * 64;
    const int t = threadIdx.x;
    #pragma unroll
    for (int p = 0; p < 4; ++p) {
        int q = p * 256 + t;
        int r = q >> 4, s = q & 15;
        float4 v = *reinterpret_cast<const float4*>(tx + (size_t)(n0 + r) * 512 + c0 + s * 4);
        tile[r][s * 4 + 0] = v.x; tile[r][s * 4 + 1] = v.y;
        tile[r][s * 4 + 2] = v.z; tile[r][s * 4 + 3] = v.w;
    }
    __syncthreads();
    #pragma unroll
    for (int p = 0; p < 4; ++p) {
        int q = p * 256 + t;
        int cc = q >> 4, s = q & 15;
        ushort4 h;
        h.x = f2bf(tile[s * 4 + 0][cc]); h.y = f2bf(tile[s * 4 + 1][cc]);
        h.z = f2bf(tile[s * 4 + 2][cc]); h.w = f2bf(tile[s * 4 + 3][cc]);
        *reinterpret_cast<ushort4*>(txt + (size_t)(c0 + cc) * 8192 + n0 + s * 4) = h;
    }
}

// ---------------------------------------------------------------------------
// colsq[j] = sum_n QKV[n,j]^2, j in [0,1024)
// ---------------------------------------------------------------------------
__global__ void k_colsq(const u16* __restrict__ QKV, float* __restrict__ colsq)
{
    const int t = threadIdx.x;
    const int c8 = t & 127, rs = t >> 7;
    float a[8];
    #pragma unroll
    for (int j = 0; j < 8; ++j) a[j] = 0.f;
    const int row0 = blockIdx.x * 64;
    for (int rr = rs; rr < 64; rr += 2) {
        uint4 u = *reinterpret_cast<const uint4*>(QKV + (size_t)(row0 + rr) * 1536 + c8 * 8);
        unsigned int w[4] = {u.x, u.y, u.z, u.w};
        #pragma unroll
        for (int q = 0; q < 4; ++q) {
            float f0 = bf2f((u16)(w[q] & 0xffffu));
            float f1 = bf2f((u16)(w[q] >> 16));
            a[2 * q]     += f0 * f0;
            a[2 * q + 1] += f1 * f1;
        }
    }
    #pragma unroll
    for (int j = 0; j < 8; ++j) atomicAdd(&colsq[c8 * 8 + j], a[j]);
}

// ---------------------------------------------------------------------------
// Per-head Gram partials: S[h,d,e] += sum_{n in chunk} K[n,h64+d]*Q[n,h64+e]
// ---------------------------------------------------------------------------
__global__ void k_gram(const u16* __restrict__ QKV, float* __restrict__ Sb)
{
    __shared__ u16 Qt[4][64];
    __shared__ u16 Kt[4][64];
    const int h = blockIdx.x >> 6;
    const int chunk = blockIdx.x & 63;
    const int t = threadIdx.x;
    const int e = t & 63;
    const int dg = t >> 6;
    float acc[16];
    #pragma unroll
    for (int k = 0; k < 16; ++k) acc[k] = 0.f;
    const int rowbase = chunk * 128;
    for (int p = 0; p < 32; ++p) {
        __syncthreads();
        if (t < 64) {
            const int mat = t >> 5, sub = t & 31, r = sub >> 3, seg = sub & 7;
            const int row = rowbase + p * 4 + r;
            const int col = (mat ? 512 : 0) + h * 64 + seg * 8;
            uint4 v = *reinterpret_cast<const uint4*>(QKV + (size_t)row * 1536 + col);
            u16* dst = mat ? &Kt[r][seg * 8] : &Qt[r][seg * 8];
            *reinterpret_cast<uint4*>(dst) = v;
        }
        __syncthreads();
        #pragma unroll
        for (int r = 0; r < 4; ++r) {
            const float q = bf2f(Qt[r][e]);
            short8v kv0 = *reinterpret_cast<const short8v*>(&Kt[r][dg * 16]);
            short8v kv1 = *reinterpret_cast<const short8v*>(&Kt[r][dg * 16 + 8]);
            #pragma unroll
            for (int k = 0; k < 8; ++k) {
                acc[k]     += bf2f((u16)kv0[k]) * q;
                acc[k + 8] += bf2f((u16)kv1[k]) * q;
            }
        }
    }
    #pragma unroll
    for (int k = 0; k < 16; ++k)
        atomicAdd(&Sb[h * 4096 + (dg * 16 + k) * 64 + e], acc[k]);
}

// ---------------------------------------------------------------------------
// attn[h,d,e] = softmax_e( S/(||k_d|| ||q_e||) * rescale[h] )
// ---------------------------------------------------------------------------
__global__ void k_softmax(const float* __restrict__ Sb, const float* __restrict__ colsq,
                          const float* __restrict__ rescale, float* __restrict__ Abuf)
{
    const int h = blockIdx.x;
    const int t = threadIdx.x;   // 64
    const float rsc = rescale[h];
    const float nq = fmaxf(sqrtf(colsq[h * 64 + t]), 1e-12f);
    for (int d = 0; d < 64; ++d) {
        const float nk = fmaxf(sqrtf(colsq[512 + h * 64 + d]), 1e-12f);
        float v = Sb[h * 4096 + d * 64 + t] / (nk * nq) * rsc;
        float m = v;
        #pragma unroll
        for (int off = 32; off > 0; off >>= 1) m = fmaxf(m, __shfl_xor(m, off, 64));
        float p = expf(v - m);
        float s = p;
        #pragma unroll
        for (int off = 32; off > 0; off >>= 1) s += __shfl_xor(s, off, 64);
        Abuf[h * 4096 + d * 64 + t] = p / s;
    }
}

// ---------------------------------------------------------------------------
// BtC[j][c]: c<512 -> fold attn with Wp; c>=512 -> W2. bsum[j] = bp[j]+b2[j].
// ---------------------------------------------------------------------------
__global__ void k_buildbt(const float* __restrict__ Abuf, const float* __restrict__ Wp,
                          const float* __restrict__ W2, const float* __restrict__ bp,
                          const float* __restrict__ b2, u16* __restrict__ BtC,
                          float* __restrict__ bsum)
{
    const int g = blockIdx.x * 256 + threadIdx.x;
    const int j = g >> 10, c = g & 1023;
    if (c < 512) {
        const int h = c >> 6, e = c & 63;
        const float* Ah = Abuf + h * 4096 + e;
        const float* Wph = Wp + (size_t)j * 512 + h * 64;
        float s = 0.f;
        #pragma unroll 8
        for (int d = 0; d < 64; ++d) s += Ah[d * 64] * Wph[d];
        BtC[(size_t)j * 1024 + c] = f2bf(s);
        if (c == 0) bsum[j] = bp[j] + b2[j];
    } else {
        BtC[(size_t)j * 1024 + c] = f2bf(W2[(size_t)j * 512 + (c - 512)]);
    }
}

// ---------------------------------------------------------------------------
extern "C" void kernel_launch(void* const* d_in, const int* in_sizes, int n_in,
                              void* d_out, int out_size, void* d_ws, size_t ws_size,
                              hipStream_t stream)
{
    const float* x_in    = (const float*)d_in[0];
    const float* task_x  = (const float*)d_in[1];
    const float* Ges     = (const float*)d_in[2];
    const float* Wq      = (const float*)d_in[3];
    const float* Wk      = (const float*)d_in[4];
    const float* Wv      = (const float*)d_in[5];
    const float* rescale = (const float*)d_in[6];
    const float* Wp      = (const float*)d_in[7];
    const float* bp      = (const float*)d_in[8];
    const float* W1      = (const float*)d_in[9];
    const float* b1      = (const float*)d_in[10];
    const float* W2      = (const float*)d_in[11];
    const float* b2      = (const float*)d_in[12];
    float* out = (float*)d_out;
    char* ws = (char*)d_ws;

    u16*   XB    = (u16*)  (ws + 0);            //  8192x512  bf16
    u16*   TXT   = (u16*)  (ws + 8388608);      //  512x8192  bf16
    u16*   QKV   = (u16*)  (ws + 16777216);     //  8192x1536 bf16
    u16*   AH    = (u16*)  (ws + 41943040);     //  8192x1024 bf16
    u16*   WqkvB = (u16*)  (ws + 58720256);     //  1536x512  bf16
    u16*   W1B   = (u16*)  (ws + 60293120);     //  512x512   bf16
    u16*   BtC   = (u16*)  (ws + 60817408);     //  512x1024  bf16
    float* colsq = (float*)(ws + 61865984);     //  1024 f32
    float* Sb    = (float*)(ws + 61870080);     //  8x64x64 f32
    float* Abuf  = (float*)(ws + 62001152);     //  8x64x64 f32
    float* bsum  = (float*)(ws + 62132224);     //  512 f32
    u16*   GesB  = (u16*)  (ws + 62134272);     //  8192x8192 bf16 (if ws fits)
    const size_t NEED = 62134272ull + 134217728ull;
    const bool pre = ws_size >= NEED;
    (void)in_sizes; (void)n_in; (void)out_size;

    hipMemsetAsync(colsq, 0, 4096 + 131072, stream);

    k_convert  <<<1024, 256, 0, stream>>>(x_in, Wq, Wk, Wv, W1, XB, WqkvB, W1B);
    k_transpose<<<dim3(128, 8), 256, 0, stream>>>(task_x, TXT);
    if (pre) k_cges<<<2048, 256, 0, stream>>>(Ges, GesB);

    // QKV = x @ [Wq;Wk;Wv]^T   (M=8192, N=1536, K=512)
    gemm_k<0, false><<<dim3(64, 24), 256, 0, stream>>>(
        XB, 512, WqkvB, 512, QKV, 1536, 512, nullptr, nullptr, 0);

    k_colsq  <<<128, 256, 0, stream>>>(QKV, colsq);
    k_gram   <<<512, 256, 0, stream>>>(QKV, Sb);
    k_softmax<<<8, 64, 0, stream>>>(Sb, colsq, rescale, Abuf);
    k_buildbt<<<2048, 256, 0, stream>>>(Abuf, Wp, W2, bp, b2, BtC, bsum);

    // guided = (Ges @ task_x) * V   (M=8192, N=512, K=8192)
    if (pre)
        gemm_k<1, false><<<dim3(64, 8), 256, 0, stream>>>(
            GesB, 8192, TXT, 8192, AH, 1024, 8192, nullptr, QKV + 1024, 1536);
    else
        gemm_k<1, true><<<dim3(64, 8), 256, 0, stream>>>(
            Ges, 8192, TXT, 8192, AH, 1024, 8192, nullptr, QKV + 1024, 1536);

    // hidden = gelu(V @ W1^T + b1)  (M=8192, N=512, K=512)
    gemm_k<2, false><<<dim3(64, 8), 256, 0, stream>>>(
        QKV + 1024, 1536, W1B, 512, AH + 512, 1024, 512, b1, nullptr, 0);

    // out = [guided|hidden] @ BtC^T + (bp+b2)  (M=8192, N=512, K=1024)
    gemm_k<3, false><<<dim3(64, 8), 256, 0, stream>>>(
        AH, 1024, BtC, 1024, out, 512, 1024, bsum, nullptr, 0);
}

// Round 7
// 369.739 us; speedup vs baseline: 1.3554x; 1.0613x over previous
//
#include <hip/hip_runtime.h>
#include <hip/hip_bf16.h>

typedef unsigned short u16;
typedef __attribute__((ext_vector_type(8))) short short8v;
typedef __attribute__((ext_vector_type(4))) float f32x4;

typedef __attribute__((address_space(3))) char lds_char;
typedef const __attribute__((address_space(1))) char g_char;

__device__ __forceinline__ u16 f2bf(float f) {
    union { float f; unsigned int u; } x; x.f = f;
    unsigned int u = x.u;
    return (u16)((u + 0x7FFFu + ((u >> 16) & 1u)) >> 16);
}
__device__ __forceinline__ float bf2f(u16 h) {
    union { unsigned int u; float f; } x; x.u = ((unsigned int)h) << 16;
    return x.f;
}
__device__ __forceinline__ u16 cvtbf(float f) {
    return __builtin_bit_cast(u16, __float2bfloat16(f));
}
__device__ __forceinline__ void gload16(const void* g, void* l) {
    __builtin_amdgcn_global_load_lds((g_char*)g, (lds_char*)l, 16, 0, 0);
}

// ---------------------------------------------------------------------------
// m97-style 128x128 bf16 MFMA GEMM, BK=64. 256 thr = 4 waves (2x2), wave tile
// 64x64 (4x4 frags of 16x16x32). SINGLE-buffer LDS (A 32KB fp32 / 16KB bf16,
// B 16KB), all staging via global_load_lds with pre-swizzled source.
// Plain 2-barrier loop: stage -> __syncthreads -> compute -> __syncthreads.
// Latency hiding comes from 3 blocks/CU co-residency (m97/m114 mechanism),
// NOT manual pipelining (rounds 2-6 showed pipelines starved at <=2 blocks).
// Split-K: blockIdx.z processes K-chunk [z*K, (z+1)*K); EPI=4 stores f32
// partial at P + z*8192*ldc.
// EPI: 0 = store bf16, 4 = store f32 partial (combine kernels do epilogues).
// AF32: A operand fp32 staged as fp32, cvt on fragment path (hardware v_cvt).
// ---------------------------------------------------------------------------
template<int EPI, bool AF32>
__global__ __launch_bounds__(256, 3) void gemm_k(
    const void* __restrict__ Ap, int lda,
    const u16* __restrict__ Bt, int ldb,
    void* __restrict__ Cp, int ldc, int K)
{
    constexpr int ATB = AF32 ? 32768 : 16384;   // A tile bytes
    __shared__ alignas(16) char smem[ATB + 16384];

    const int t     = threadIdx.x;
    const int lane  = t & 63;
    const int wid   = t >> 6;
    const int m0    = blockIdx.x * 128;
    const int n0    = blockIdx.y * 128;
    const int kbase = blockIdx.z * K;
    const int wr    = wid >> 1, wc = wid & 1;
    const int lr    = lane & 15, q4 = lane >> 4;

    f32x4 acc[4][4];
    #pragma unroll
    for (int i = 0; i < 4; ++i)
        #pragma unroll
        for (int j = 0; j < 4; ++j)
            acc[i][j] = (f32x4){0.f, 0.f, 0.f, 0.f};

    const int nsteps = K >> 6;
    for (int kt = 0; kt < nsteps; ++kt) {
        const int k0 = kbase + (kt << 6);
        // ---- stage A (DMA, pre-swizzled source -> linear LDS) ----
        if constexpr (AF32) {
            const float* A32 = (const float*)Ap;
            #pragma unroll
            for (int p = 0; p < 8; ++p) {
                int o   = p * 4096 + t * 16;
                int row = o >> 8;
                int cb  = (o & 255) ^ ((row & 15) << 4);
                gload16(A32 + (size_t)(m0 + row) * (size_t)lda + k0 + (cb >> 2),
                        smem + o);
            }
        } else {
            const u16* A16 = (const u16*)Ap;
            #pragma unroll
            for (int p = 0; p < 4; ++p) {
                int o   = p * 4096 + t * 16;
                int row = o >> 7;
                int cb  = (o & 127) ^ ((row & 7) << 4);
                gload16(A16 + (size_t)(m0 + row) * (size_t)lda + k0 + (cb >> 1),
                        smem + o);
            }
        }
        // ---- stage B ----
        #pragma unroll
        for (int p = 0; p < 4; ++p) {
            int o   = p * 4096 + t * 16;
            int row = o >> 7;
            int cb  = (o & 127) ^ ((row & 7) << 4);
            gload16(Bt + (size_t)(n0 + row) * (size_t)ldb + k0 + (cb >> 1),
                    smem + ATB + o);
        }
        __syncthreads();   // vmcnt(0) drain + barrier: tile visible to all waves

        // ---- compute ----
        #pragma unroll
        for (int kh = 0; kh < 2; ++kh) {
            short8v a[4], b[4];
            #pragma unroll
            for (int i = 0; i < 4; ++i) {
                int ar = wr * 64 + i * 16 + lr;
                if constexpr (AF32) {
                    int cb0 = kh * 128 + q4 * 32;
                    int sw  = (ar & 15) << 4;
                    f32x4 f0 = *(const f32x4*)(smem + ar * 256 + (cb0 ^ sw));
                    f32x4 f1 = *(const f32x4*)(smem + ar * 256 + ((cb0 + 16) ^ sw));
                    short8v av;
                    #pragma unroll
                    for (int j = 0; j < 4; ++j) {
                        av[j]     = (short)cvtbf(f0[j]);
                        av[j + 4] = (short)cvtbf(f1[j]);
                    }
                    a[i] = av;
                } else {
                    a[i] = *(const short8v*)(smem + ar * 128 +
                            ((kh * 64 + q4 * 16) ^ ((ar & 7) << 4)));
                }
            }
            #pragma unroll
            for (int i = 0; i < 4; ++i) {
                int br = wc * 64 + i * 16 + lr;
                b[i] = *(const short8v*)(smem + ATB + br * 128 +
                        ((kh * 64 + q4 * 16) ^ ((br & 7) << 4)));
            }
            #pragma unroll
            for (int mi = 0; mi < 4; ++mi)
                #pragma unroll
                for (int ni = 0; ni < 4; ++ni)
                    acc[mi][ni] = __builtin_amdgcn_mfma_f32_16x16x32_bf16(
                        a[mi], b[ni], acc[mi][ni], 0, 0, 0);
        }
        __syncthreads();   // all reads done before next stage overwrites
    }

    // ---- epilogue ----
    const size_t zoff = (size_t)blockIdx.z * 8192ull * (size_t)ldc;
    #pragma unroll
    for (int mi = 0; mi < 4; ++mi) {
        #pragma unroll
        for (int ni = 0; ni < 4; ++ni) {
            const int gc = n0 + wc * 64 + ni * 16 + lr;
            #pragma unroll
            for (int j = 0; j < 4; ++j) {
                const int gr = m0 + wr * 64 + mi * 16 + q4 * 4 + j;
                float v = acc[mi][ni][j];
                if constexpr (EPI == 0) {
                    ((u16*)Cp)[(size_t)gr * ldc + gc] = f2bf(v);
                } else {
                    ((float*)Cp)[zoff + (size_t)gr * ldc + gc] = v;
                }
            }
        }
    }
}

// ---------------------------------------------------------------------------
// Split-K combine + fused epilogues over [8192 x 512].
// MODE 1: AH[r][c]      = bf16( (sum_z P) * V[r][c] )        (guided * V)
// MODE 2: AH[r][512+c]  = bf16( gelu( sum_z P + b1[c] ) )    (MLP hidden)
// MODE 3: out[r][c]     = sum_z P + bsum[c]                   (final, f32)
// ---------------------------------------------------------------------------
template<int KZ, int MODE>
__global__ void k_cmb(const float* __restrict__ P, const u16* __restrict__ QKV,
                      const float* __restrict__ bvec, void* __restrict__ dst)
{
    for (int i = blockIdx.x * 256 + threadIdx.x; i < 1048576;
         i += gridDim.x * 256) {
        const int r = i >> 7, c = (i & 127) * 4;
        f32x4 s = ((const f32x4*)P)[i];
        #pragma unroll
        for (int z = 1; z < KZ; ++z) {
            f32x4 q = ((const f32x4*)P)[(size_t)z * 1048576 + i];
            s[0] += q[0]; s[1] += q[1]; s[2] += q[2]; s[3] += q[3];
        }
        if constexpr (MODE == 1) {
            ushort4 v = *(const ushort4*)(QKV + (size_t)r * 1536 + 1024 + c);
            ushort4 o;
            o.x = cvtbf(s[0] * bf2f(v.x)); o.y = cvtbf(s[1] * bf2f(v.y));
            o.z = cvtbf(s[2] * bf2f(v.z)); o.w = cvtbf(s[3] * bf2f(v.w));
            *(ushort4*)((u16*)dst + (size_t)r * 1024 + c) = o;
        } else if constexpr (MODE == 2) {
            float4 b = *(const float4*)(bvec + c);
            float x0 = s[0] + b.x, x1 = s[1] + b.y, x2 = s[2] + b.z, x3 = s[3] + b.w;
            ushort4 o;
            o.x = cvtbf(0.5f * x0 * (1.0f + erff(x0 * 0.70710678118f)));
            o.y = cvtbf(0.5f * x1 * (1.0f + erff(x1 * 0.70710678118f)));
            o.z = cvtbf(0.5f * x2 * (1.0f + erff(x2 * 0.70710678118f)));
            o.w = cvtbf(0.5f * x3 * (1.0f + erff(x3 * 0.70710678118f)));
            *(ushort4*)((u16*)dst + (size_t)r * 1024 + 512 + c) = o;
        } else {
            float4 b = *(const float4*)(bvec + c);
            float4 o = {s[0] + b.x, s[1] + b.y, s[2] + b.z, s[3] + b.w};
            *(float4*)((float*)dst + (size_t)r * 512 + c) = o;
        }
    }
}

// ---------------------------------------------------------------------------
// Convert Wq|Wk|Wv (concat) and W1 to bf16 (x_in/Ges consumed fp32 directly).
// ---------------------------------------------------------------------------
__global__ void k_convert(const float* __restrict__ Wq, const float* __restrict__ Wk,
                          const float* __restrict__ Wv, const float* __restrict__ W1,
                          u16* __restrict__ WqkvB, u16* __restrict__ W1B)
{
    const int C2 = 196608;   // Wqkv float4 chunks
    const int C3 = 65536;    // W1 chunks
    for (int i = blockIdx.x * blockDim.x + threadIdx.x; i < C2 + C3;
         i += gridDim.x * blockDim.x) {
        const float* src; u16* dst;
        if (i < C2) {
            int e = i * 4;
            if (e < 262144)      src = Wq + e;
            else if (e < 524288) src = Wk + (e - 262144);
            else                 src = Wv + (e - 524288);
            dst = WqkvB + e;
        } else {
            int e = (i - C2) * 4;
            src = W1 + e; dst = W1B + e;
        }
        float4 v = *reinterpret_cast<const float4*>(src);
        ushort4 h;
        h.x = f2bf(v.x); h.y = f2bf(v.y); h.z = f2bf(v.z); h.w = f2bf(v.w);
        *reinterpret_cast<ushort4*>(dst) = h;
    }
}

// ---------------------------------------------------------------------------
// TXT[c][m] = bf16(task_x[m][c])  — 64x64 tiles through LDS.
// ---------------------------------------------------------------------------
__global__ void k_transpose(const float* __restrict__ tx, u16* __restrict__ txt)
{
    __shared__ float tile[64][65];
    const int n0 = blockIdx.x * 64;
    const int c0 = blockIdx.y * 64;
    const int t = threadIdx.x;
    #pragma unroll
    for (int p = 0; p < 4; ++p) {
        int q = p * 256 + t;
        int r = q >> 4, s = q & 15;
        float4 v = *reinterpret_cast<const float4*>(tx + (size_t)(n0 + r) * 512 + c0 + s * 4);
        tile[r][s * 4 + 0] = v.x; tile[r][s * 4 + 1] = v.y;
        tile[r][s * 4 + 2] = v.z; tile[r][s * 4 + 3] = v.w;
    }
    __syncthreads();
    #pragma unroll
    for (int p = 0; p < 4; ++p) {
        int q = p * 256 + t;
        int cc = q >> 4, s = q & 15;
        ushort4 h;
        h.x = f2bf(tile[s * 4 + 0][cc]); h.y = f2bf(tile[s * 4 + 1][cc]);
        h.z = f2bf(tile[s * 4 + 2][cc]); h.w = f2bf(tile[s * 4 + 3][cc]);
        *reinterpret_cast<ushort4*>(txt + (size_t)(c0 + cc) * 8192 + n0 + s * 4) = h;
    }
}

// ---------------------------------------------------------------------------
// colsq[j] = sum_n QKV[n,j]^2, j in [0,1024)
// ---------------------------------------------------------------------------
__global__ void k_colsq(const u16* __restrict__ QKV, float* __restrict__ colsq)
{
    const int t = threadIdx.x;
    const int c8 = t & 127, rs = t >> 7;
    float a[8];
    #pragma unroll
    for (int j = 0; j < 8; ++j) a[j] = 0.f;
    const int row0 = blockIdx.x * 64;
    for (int rr = rs; rr < 64; rr += 2) {
        uint4 u = *reinterpret_cast<const uint4*>(QKV + (size_t)(row0 + rr) * 1536 + c8 * 8);
        unsigned int w[4] = {u.x, u.y, u.z, u.w};
        #pragma unroll
        for (int q = 0; q < 4; ++q) {
            float f0 = bf2f((u16)(w[q] & 0xffffu));
            float f1 = bf2f((u16)(w[q] >> 16));
            a[2 * q]     += f0 * f0;
            a[2 * q + 1] += f1 * f1;
        }
    }
    #pragma unroll
    for (int j = 0; j < 8; ++j) atomicAdd(&colsq[c8 * 8 + j], a[j]);
}

// ---------------------------------------------------------------------------
// Per-head Gram partials: S[h,d,e] += sum_{n in chunk} K[n,h64+d]*Q[n,h64+e]
// ---------------------------------------------------------------------------
__global__ void k_gram(const u16* __restrict__ QKV, float* __restrict__ Sb)
{
    __shared__ u16 Qt[4][64];
    __shared__ u16 Kt[4][64];
    const int h = blockIdx.x >> 6;
    const int chunk = blockIdx.x & 63;
    const int t = threadIdx.x;
    const int e = t & 63;
    const int dg = t >> 6;
    float acc[16];
    #pragma unroll
    for (int k = 0; k < 16; ++k) acc[k] = 0.f;
    const int rowbase = chunk * 128;
    for (int p = 0; p < 32; ++p) {
        __syncthreads();
        if (t < 64) {
            const int mat = t >> 5, sub = t & 31, r = sub >> 3, seg = sub & 7;
            const int row = rowbase + p * 4 + r;
            const int col = (mat ? 512 : 0) + h * 64 + seg * 8;
            uint4 v = *reinterpret_cast<const uint4*>(QKV + (size_t)row * 1536 + col);
            u16* dst = mat ? &Kt[r][seg * 8] : &Qt[r][seg * 8];
            *reinterpret_cast<uint4*>(dst) = v;
        }
        __syncthreads();
        #pragma unroll
        for (int r = 0; r < 4; ++r) {
            const float q = bf2f(Qt[r][e]);
            short8v kv0 = *reinterpret_cast<const short8v*>(&Kt[r][dg * 16]);
            short8v kv1 = *reinterpret_cast<const short8v*>(&Kt[r][dg * 16 + 8]);
            #pragma unroll
            for (int k = 0; k < 8; ++k) {
                acc[k]     += bf2f((u16)kv0[k]) * q;
                acc[k + 8] += bf2f((u16)kv1[k]) * q;
            }
        }
    }
    #pragma unroll
    for (int k = 0; k < 16; ++k)
        atomicAdd(&Sb[h * 4096 + (dg * 16 + k) * 64 + e], acc[k]);
}

// ---------------------------------------------------------------------------
// attn[h,d,e] = softmax_e( S/(||k_d|| ||q_e||) * rescale[h] )
// ---------------------------------------------------------------------------
__global__ void k_softmax(const float* __restrict__ Sb, const float* __restrict__ colsq,
                          const float* __restrict__ rescale, float* __restrict__ Abuf)
{
    const int h = blockIdx.x;
    const int t = threadIdx.x;   // 64
    const float rsc = rescale[h];
    const float nq = fmaxf(sqrtf(colsq[h * 64 + t]), 1e-12f);
    for (int d = 0; d < 64; ++d) {
        const float nk = fmaxf(sqrtf(colsq[512 + h * 64 + d]), 1e-12f);
        float v = Sb[h * 4096 + d * 64 + t] / (nk * nq) * rsc;
        float m = v;
        #pragma unroll
        for (int off = 32; off > 0; off >>= 1) m = fmaxf(m, __shfl_xor(m, off, 64));
        float p = expf(v - m);
        float s = p;
        #pragma unroll
        for (int off = 32; off > 0; off >>= 1) s += __shfl_xor(s, off, 64);
        Abuf[h * 4096 + d * 64 + t] = p / s;
    }
}

// ---------------------------------------------------------------------------
// BtC[j][c]: c<512 -> fold attn with Wp; c>=512 -> W2. bsum[j] = bp[j]+b2[j].
// ---------------------------------------------------------------------------
__global__ void k_buildbt(const float* __restrict__ Abuf, const float* __restrict__ Wp,
                          const float* __restrict__ W2, const float* __restrict__ bp,
                          const float* __restrict__ b2, u16* __restrict__ BtC,
                          float* __restrict__ bsum)
{
    const int g = blockIdx.x * 256 + threadIdx.x;
    const int j = g >> 10, c = g & 1023;
    if (c < 512) {
        const int h = c >> 6, e = c & 63;
        const float* Ah = Abuf + h * 4096 + e;
        const float* Wph = Wp + (size_t)j * 512 + h * 64;
        float s = 0.f;
        #pragma unroll 8
        for (int d = 0; d < 64; ++d) s += Ah[d * 64] * Wph[d];
        BtC[(size_t)j * 1024 + c] = f2bf(s);
        if (c == 0) bsum[j] = bp[j] + b2[j];
    } else {
        BtC[(size_t)j * 1024 + c] = f2bf(W2[(size_t)j * 512 + (c - 512)]);
    }
}

// ---------------------------------------------------------------------------
extern "C" void kernel_launch(void* const* d_in, const int* in_sizes, int n_in,
                              void* d_out, int out_size, void* d_ws, size_t ws_size,
                              hipStream_t stream)
{
    const float* x_in    = (const float*)d_in[0];
    const float* task_x  = (const float*)d_in[1];
    const float* Ges     = (const float*)d_in[2];
    const float* Wq      = (const float*)d_in[3];
    const float* Wk      = (const float*)d_in[4];
    const float* Wv      = (const float*)d_in[5];
    const float* rescale = (const float*)d_in[6];
    const float* Wp      = (const float*)d_in[7];
    const float* bp      = (const float*)d_in[8];
    const float* W1      = (const float*)d_in[9];
    const float* b1      = (const float*)d_in[10];
    const float* W2      = (const float*)d_in[11];
    const float* b2      = (const float*)d_in[12];
    float* out = (float*)d_out;
    char* ws = (char*)d_ws;

    u16*   TXT   = (u16*)  (ws + 0);            //  512x8192  bf16 (8 MB)
    u16*   QKV   = (u16*)  (ws + 8388608);      //  8192x1536 bf16 (25 MB)
    u16*   AH    = (u16*)  (ws + 33554432);     //  8192x1024 bf16 (17 MB)
    u16*   WqkvB = (u16*)  (ws + 50331648);     //  1536x512  bf16
    u16*   W1B   = (u16*)  (ws + 51904512);     //  512x512   bf16
    u16*   BtC   = (u16*)  (ws + 52428800);     //  512x1024  bf16
    float* colsq = (float*)(ws + 53477376);     //  1024 f32
    float* Sb    = (float*)(ws + 53481472);     //  8x64x64 f32
    float* Abuf  = (float*)(ws + 53612544);     //  8x64x64 f32
    float* bsum  = (float*)(ws + 53743616);     //  512 f32
    float* P     = (float*)(ws + 53745664);     //  up to 4 x 8192x512 f32 (64 MB)
    (void)in_sizes; (void)n_in; (void)out_size; (void)ws_size;

    hipMemsetAsync(colsq, 0, 135168, stream);   // colsq + Sb

    k_convert  <<<512, 256, 0, stream>>>(Wq, Wk, Wv, W1, WqkvB, W1B);
    k_transpose<<<dim3(128, 8), 256, 0, stream>>>(task_x, TXT);

    // QKV = x @ [Wq;Wk;Wv]^T  (M=8192, N=1536, K=512; A = x_in fp32; 768 blk)
    gemm_k<0, true><<<dim3(64, 12, 1), 256, 0, stream>>>(
        x_in, 512, WqkvB, 512, QKV, 1536, 512);

    k_colsq  <<<128, 256, 0, stream>>>(QKV, colsq);
    k_gram   <<<512, 256, 0, stream>>>(QKV, Sb);
    k_softmax<<<8, 64, 0, stream>>>(Sb, colsq, rescale, Abuf);
    k_buildbt<<<2048, 256, 0, stream>>>(Abuf, Wp, W2, bp, b2, BtC, bsum);

    // guided partials: Ges @ TXT^T  (M=8192, N=512, K=8192, split-K=4 -> 1024 blk)
    gemm_k<4, true><<<dim3(64, 4, 4), 256, 0, stream>>>(
        Ges, 8192, TXT, 8192, P, 512, 2048);
    k_cmb<4, 1><<<1024, 256, 0, stream>>>(P, QKV, nullptr, AH);

    // hidden partials: V @ W1^T  (K=512, split-K=2 -> 512 blk)
    gemm_k<4, false><<<dim3(64, 4, 2), 256, 0, stream>>>(
        QKV + 1024, 1536, W1B, 512, P, 512, 256);
    k_cmb<2, 2><<<1024, 256, 0, stream>>>(P, nullptr, b1, AH);

    // final partials: [guided|hidden] @ BtC^T  (K=1024, split-K=2 -> 512 blk)
    gemm_k<4, false><<<dim3(64, 4, 2), 256, 0, stream>>>(
        AH, 1024, BtC, 1024, P, 512, 512);
    k_cmb<2, 3><<<1024, 256, 0, stream>>>(P, nullptr, bsum, out);
}